// Round 5
// baseline (444.623 us; speedup 1.0000x reference)
//
#include <hip/hip_runtime.h>
#include <hip/hip_bf16.h>
#include <hip/hip_cooperative_groups.h>

namespace cg = cooperative_groups;

// Problem constants
#define BATCH 16
#define CIN 8
#define COUT 8
#define HH 512
#define WW 512
constexpr int TPX = 4;                        // pixels per thread along h
constexpr float EPS = 1e-5f;
constexpr float NPC = (float)BATCH * HH * WW; // per-channel element count
constexpr int NBLK = 1024;                    // coop grid: 4 blocks/CU x 256 CU
constexpr int NVIRT = 2 * (HH / TPX) * BATCH; // 4096 virtual conv tiles
constexpr int SUBT = NVIRT / NBLK;            // 4 subtiles per block

// ---------------- fused cooperative kernel ----------------
// Phase A: conv (R0's proven 4-tall tile) x SUBT subtiles -> bf16 ws + stats
// grid.sync()
// Phase B: BN+ReLU from bf16 ws, grid-strided 16 iterations
__global__ __launch_bounds__(256, 4)
void fused_kernel(const float* __restrict__ x,
                  const float* __restrict__ lin_w,
                  const float* __restrict__ gamma,
                  const float* __restrict__ beta,
                  __hip_bfloat16* __restrict__ ws_y,
                  float* __restrict__ stats,
                  float* __restrict__ out) {
    float s[COUT], q[COUT];
#pragma unroll
    for (int oc = 0; oc < COUT; ++oc) { s[oc] = 0.f; q[oc] = 0.f; }

    for (int t = 0; t < SUBT; ++t) {
        const int v  = blockIdx.x * SUBT + t;   // 0..4095 virtual tile id
        const int wx = v & 1;
        const int hy = (v >> 1) & 127;
        const int b  = v >> 8;
        const int w  = wx * 256 + threadIdx.x;  // 0..511
        const int h0 = hy * TPX;                // 0..508

        float acc[TPX][COUT];
#pragma unroll
        for (int px = 0; px < TPX; ++px)
#pragma unroll
            for (int oc = 0; oc < COUT; ++oc) acc[px][oc] = 0.f;

        const float* xb = x + (size_t)b * CIN * HH * WW;
        const int wm = max(w - 1, 0), wp = min(w + 1, WW - 1);
        const bool wl = (w >= 1), wr = (w <= WW - 2);

        for (int ic = 0; ic < CIN; ++ic) {
            const float* xc = xb + (size_t)ic * HH * WW;
            float xv[TPX + 2][3];
#pragma unroll
            for (int r = 0; r < TPX + 2; ++r) {
                const int hraw = h0 - 1 + r;
                const int hcl = min(max(hraw, 0), HH - 1);
                const bool vr = (hraw >= 0) && (hraw < HH);
                const float* xr = xc + (size_t)hcl * WW;
                float a0 = xr[wm], a1 = xr[w], a2 = xr[wp];
                xv[r][0] = (vr && wl) ? a0 : 0.f;
                xv[r][1] = vr ? a1 : 0.f;
                xv[r][2] = (vr && wr) ? a2 : 0.f;
            }
#pragma unroll
            for (int kh = 0; kh < 3; ++kh) {
#pragma unroll
                for (int kw = 0; kw < 3; ++kw) {
                    const int p = kh * 3 + kw;
#pragma unroll
                    for (int px = 0; px < TPX; ++px) {
                        const float xval = xv[kh + px][kw];
#pragma unroll
                        for (int oc = 0; oc < COUT; ++oc) {
                            // uniform address -> s_load; SGPR operand in v_fmac
                            acc[px][oc] = fmaf(xval, lin_w[(ic * COUT + oc) * 9 + p],
                                               acc[px][oc]);
                        }
                    }
                }
            }
        }

        // fold into running per-thread stats; store bf16 ws
#pragma unroll
        for (int oc = 0; oc < COUT; ++oc) {
#pragma unroll
            for (int px = 0; px < TPX; ++px) {
                s[oc] += acc[px][oc];
                q[oc] = fmaf(acc[px][oc], acc[px][oc], q[oc]);
                size_t oidx = (((size_t)(b * COUT + oc)) * HH + (h0 + px)) * WW + w;
                ws_y[oidx] = __float2bfloat16(acc[px][oc]);
            }
        }
    }

    // wave (64-lane) reduce, then block reduce, one atomic set per block
#pragma unroll
    for (int off = 32; off > 0; off >>= 1) {
#pragma unroll
        for (int oc = 0; oc < COUT; ++oc) {
            s[oc] += __shfl_down(s[oc], off);
            q[oc] += __shfl_down(q[oc], off);
        }
    }
    __shared__ float reds[4][2 * COUT];
    const int lane = threadIdx.x & 63, wv = threadIdx.x >> 6;
    if (lane == 0) {
#pragma unroll
        for (int oc = 0; oc < COUT; ++oc) {
            reds[wv][oc] = s[oc];
            reds[wv][COUT + oc] = q[oc];
        }
    }
    __syncthreads();
    if (threadIdx.x < 2 * COUT) {
        float vsum = reds[0][threadIdx.x] + reds[1][threadIdx.x] +
                     reds[2][threadIdx.x] + reds[3][threadIdx.x];
        atomicAdd(&stats[threadIdx.x], vsum);
    }

    cg::this_grid().sync();  // all conv done; stats final & visible

    // -------- Phase B: BN + ReLU from bf16 ws --------
    const size_t base = ((size_t)blockIdx.x * 256 + threadIdx.x) * 8;
    const size_t stride = (size_t)NBLK * 256 * 8;      // 2^21
    // oc depends only on bits 18..20 of the index; stride is 2^21 -> constant
    const int oc = (int)((base >> 18) & 7);
    const volatile float* vst = stats;                  // skip L1 after sync
    const float mean = vst[oc] * (1.f / NPC);
    const float var  = vst[COUT + oc] * (1.f / NPC) - mean * mean;
    const float rstd = rsqrtf(var + EPS);
    const float sc = gamma[oc] * rstd;
    const float sh = fmaf(-mean, sc, beta[oc]);

    const size_t n_elem = (size_t)BATCH * COUT * HH * WW;
    for (size_t i8 = base; i8 < n_elem; i8 += stride) {
        const uint4 u = *(const uint4*)((const char*)ws_y + i8 * 2);
        float v[8];
        v[0] = __uint_as_float(u.x << 16);
        v[1] = __uint_as_float(u.x & 0xffff0000u);
        v[2] = __uint_as_float(u.y << 16);
        v[3] = __uint_as_float(u.y & 0xffff0000u);
        v[4] = __uint_as_float(u.z << 16);
        v[5] = __uint_as_float(u.z & 0xffff0000u);
        v[6] = __uint_as_float(u.w << 16);
        v[7] = __uint_as_float(u.w & 0xffff0000u);
        float4 o0, o1;
        o0.x = fmaxf(fmaf(v[0], sc, sh), 0.f);
        o0.y = fmaxf(fmaf(v[1], sc, sh), 0.f);
        o0.z = fmaxf(fmaf(v[2], sc, sh), 0.f);
        o0.w = fmaxf(fmaf(v[3], sc, sh), 0.f);
        o1.x = fmaxf(fmaf(v[4], sc, sh), 0.f);
        o1.y = fmaxf(fmaf(v[5], sc, sh), 0.f);
        o1.z = fmaxf(fmaf(v[6], sc, sh), 0.f);
        o1.w = fmaxf(fmaf(v[7], sc, sh), 0.f);
        *(float4*)(out + i8) = o0;
        *(float4*)(out + i8 + 4) = o1;
    }
}

// ---------------- fallback: two-pass recompute (no ws, no coop) ----------------
// MODE 1: conv -> stats atomics only
// MODE 2: conv recompute -> normalize -> fp32 out (reads stats)
template <int MODE>
__global__ __launch_bounds__(256, 4)
void conv_kernel(const float* __restrict__ x,
                 const float* __restrict__ lin_w,
                 const float* __restrict__ gamma,
                 const float* __restrict__ beta,
                 __hip_bfloat16* __restrict__ ws_y,
                 float* __restrict__ stats,
                 float* __restrict__ out) {
    const int w  = blockIdx.x * 256 + threadIdx.x;
    const int h0 = blockIdx.y * TPX;
    const int b  = blockIdx.z;

    float acc[TPX][COUT];
#pragma unroll
    for (int px = 0; px < TPX; ++px)
#pragma unroll
        for (int oc = 0; oc < COUT; ++oc) acc[px][oc] = 0.f;

    const float* xb = x + (size_t)b * CIN * HH * WW;
    const int wm = max(w - 1, 0), wp = min(w + 1, WW - 1);
    const bool wl = (w >= 1), wr = (w <= WW - 2);

    for (int ic = 0; ic < CIN; ++ic) {
        const float* xc = xb + (size_t)ic * HH * WW;
        float xv[TPX + 2][3];
#pragma unroll
        for (int r = 0; r < TPX + 2; ++r) {
            const int hraw = h0 - 1 + r;
            const int hcl = min(max(hraw, 0), HH - 1);
            const bool vr = (hraw >= 0) && (hraw < HH);
            const float* xr = xc + (size_t)hcl * WW;
            float a0 = xr[wm], a1 = xr[w], a2 = xr[wp];
            xv[r][0] = (vr && wl) ? a0 : 0.f;
            xv[r][1] = vr ? a1 : 0.f;
            xv[r][2] = (vr && wr) ? a2 : 0.f;
        }
#pragma unroll
        for (int kh = 0; kh < 3; ++kh)
#pragma unroll
            for (int kw = 0; kw < 3; ++kw) {
                const int p = kh * 3 + kw;
#pragma unroll
                for (int px = 0; px < TPX; ++px) {
                    const float xval = xv[kh + px][kw];
#pragma unroll
                    for (int oc = 0; oc < COUT; ++oc)
                        acc[px][oc] = fmaf(xval, lin_w[(ic * COUT + oc) * 9 + p],
                                           acc[px][oc]);
                }
            }
    }

    if (MODE == 1) {
        float s[COUT], q[COUT];
#pragma unroll
        for (int oc = 0; oc < COUT; ++oc) {
            float ss = 0.f, qq = 0.f;
#pragma unroll
            for (int px = 0; px < TPX; ++px) {
                ss += acc[px][oc];
                qq = fmaf(acc[px][oc], acc[px][oc], qq);
            }
            s[oc] = ss; q[oc] = qq;
        }
#pragma unroll
        for (int off = 32; off > 0; off >>= 1)
#pragma unroll
            for (int oc = 0; oc < COUT; ++oc) {
                s[oc] += __shfl_down(s[oc], off);
                q[oc] += __shfl_down(q[oc], off);
            }
        __shared__ float reds[4][2 * COUT];
        const int lane = threadIdx.x & 63, wv = threadIdx.x >> 6;
        if (lane == 0)
#pragma unroll
            for (int oc = 0; oc < COUT; ++oc) {
                reds[wv][oc] = s[oc];
                reds[wv][COUT + oc] = q[oc];
            }
        __syncthreads();
        if (threadIdx.x < 2 * COUT) {
            float vsum = reds[0][threadIdx.x] + reds[1][threadIdx.x] +
                         reds[2][threadIdx.x] + reds[3][threadIdx.x];
            atomicAdd(&stats[threadIdx.x], vsum);
        }
    } else {
#pragma unroll
        for (int oc = 0; oc < COUT; ++oc) {
            const float mean = stats[oc] * (1.f / NPC);
            const float var  = stats[COUT + oc] * (1.f / NPC) - mean * mean;
            const float rstd = rsqrtf(var + EPS);
            const float sc = gamma[oc] * rstd;
            const float sh = fmaf(-mean, sc, beta[oc]);
#pragma unroll
            for (int px = 0; px < TPX; ++px) {
                size_t oidx = (((size_t)(b * COUT + oc)) * HH + (h0 + px)) * WW + w;
                out[oidx] = fmaxf(fmaf(acc[px][oc], sc, sh), 0.f);
            }
        }
    }
}

extern "C" void kernel_launch(void* const* d_in, const int* in_sizes, int n_in,
                              void* d_out, int out_size, void* d_ws, size_t ws_size,
                              hipStream_t stream) {
    const float* x     = (const float*)d_in[0];
    const float* lin_w = (const float*)d_in[1];
    // d_in[2] = lin_b: constant per-channel shift, BatchNorm removes it -> unused.
    const float* gamma = (const float*)d_in[3];
    const float* beta  = (const float*)d_in[4];
    float* out = (float*)d_out;

    float* stats = (float*)d_ws;                                   // 16 floats
    __hip_bfloat16* ws_y = (__hip_bfloat16*)((char*)d_ws + 4096);  // bf16 conv out

    const size_t n_elem = (size_t)BATCH * COUT * HH * WW;          // 33,554,432
    const size_t need = 4096 + n_elem * 2;

    (void)hipMemsetAsync(d_ws, 0, 256, stream);  // zero stats

    bool done = false;
    if (ws_size >= need) {
        void* args[7] = {(void*)&x, (void*)&lin_w, (void*)&gamma, (void*)&beta,
                         (void*)&ws_y, (void*)&stats, (void*)&out};
        hipError_t ce = hipLaunchCooperativeKernel(
            reinterpret_cast<void*>(fused_kernel), dim3(NBLK), dim3(256),
            args, 0, stream);
        done = (ce == hipSuccess);
    }
    if (!done) {
        // two-pass recompute fallback (no ws, no cooperative launch)
        dim3 grid(WW / 256, HH / TPX, BATCH);
        conv_kernel<1><<<grid, 256, 0, stream>>>(x, lin_w, gamma, beta, ws_y, stats, out);
        conv_kernel<2><<<grid, 256, 0, stream>>>(x, lin_w, gamma, beta, ws_y, stats, out);
    }
}

// Round 6
// 300.410 us; speedup vs baseline: 1.4801x; 1.4801x over previous
//
#include <hip/hip_runtime.h>
#include <hip/hip_bf16.h>

// Problem constants
#define BATCH 16
#define CIN 8
#define COUT 8
#define HH 512
#define WW 512
constexpr int TPX = 4;                        // pixels per thread along h
constexpr float EPS = 1e-5f;
constexpr float NPC = (float)BATCH * HH * WW; // per-channel element count

typedef float f32x2 __attribute__((ext_vector_type(2)));

// MODE 0: conv -> bf16 ws + stats atomics
// MODE 1: conv -> stats atomics only (no ws write)
// MODE 2: conv recompute -> normalize -> fp32 out (reads stats)
//
// R6 changes vs R0 (97us conv):
//  - ic loop fully unrolled: weight s_loads hoistable across FMA blocks
//    (runtime ic loop re-issued ~72 s_loads + lgkmcnt wait every iteration)
//  - acc as float2 over oc pairs + __builtin_elementwise_fma ->
//    v_pk_fma_f32 (2 fp32 FMA/instr) halves FMA issue cycles
template <int MODE>
__global__ __launch_bounds__(256, 4)
void conv_kernel(const float* __restrict__ x,
                 const float* __restrict__ lin_w,
                 const float* __restrict__ gamma,
                 const float* __restrict__ beta,
                 __hip_bfloat16* __restrict__ ws_y,
                 float* __restrict__ stats,
                 float* __restrict__ out) {
    const int w  = blockIdx.x * 256 + threadIdx.x;   // 0..511
    const int h0 = blockIdx.y * TPX;                  // 0..508
    const int b  = blockIdx.z;

    f32x2 acc[TPX][COUT / 2];                         // oc pairs
#pragma unroll
    for (int px = 0; px < TPX; ++px)
#pragma unroll
        for (int j = 0; j < COUT / 2; ++j) acc[px][j] = (f32x2)(0.f);

    const float* xb = x + (size_t)b * CIN * HH * WW;
    const int wm = max(w - 1, 0), wp = min(w + 1, WW - 1);
    const bool wl = (w >= 1), wr = (w <= WW - 2);

    // hoisted row info (independent of ic)
    int rowoff[TPX + 2];
    bool rv[TPX + 2];
#pragma unroll
    for (int r = 0; r < TPX + 2; ++r) {
        const int hraw = h0 - 1 + r;
        const int hcl = min(max(hraw, 0), HH - 1);
        rowoff[r] = hcl * WW;
        rv[r] = (hraw >= 0) && (hraw < HH);
    }

#pragma unroll
    for (int ic = 0; ic < CIN; ++ic) {
        const float* xc = xb + (size_t)ic * HH * WW;
        float xv[TPX + 2][3];
#pragma unroll
        for (int r = 0; r < TPX + 2; ++r) {
            const float* xr = xc + rowoff[r];
            const bool vr = rv[r];
            float a0 = xr[wm], a1 = xr[w], a2 = xr[wp];
            xv[r][0] = (vr && wl) ? a0 : 0.f;
            xv[r][1] = vr ? a1 : 0.f;
            xv[r][2] = (vr && wr) ? a2 : 0.f;
        }
#pragma unroll
        for (int kh = 0; kh < 3; ++kh) {
#pragma unroll
            for (int kw = 0; kw < 3; ++kw) {
                const int p = kh * 3 + kw;
#pragma unroll
                for (int px = 0; px < TPX; ++px) {
                    const float xval = xv[kh + px][kw];
                    const f32x2 xb2 = {xval, xval};
#pragma unroll
                    for (int j = 0; j < COUT / 2; ++j) {
                        // weights: uniform address -> s_load; pair over oc
                        const f32x2 wv2 = {
                            lin_w[(ic * COUT + 2 * j) * 9 + p],
                            lin_w[(ic * COUT + 2 * j + 1) * 9 + p]};
                        acc[px][j] = __builtin_elementwise_fma(xb2, wv2, acc[px][j]);
                    }
                }
            }
        }
    }

    if (MODE == 0 || MODE == 1) {
        // per-thread channel sums (as float2 pairs)
        f32x2 s[COUT / 2], q[COUT / 2];
#pragma unroll
        for (int j = 0; j < COUT / 2; ++j) {
            f32x2 ss = (f32x2)(0.f), qq = (f32x2)(0.f);
#pragma unroll
            for (int px = 0; px < TPX; ++px) {
                ss += acc[px][j];
                qq = __builtin_elementwise_fma(acc[px][j], acc[px][j], qq);
            }
            s[j] = ss; q[j] = qq;
        }
        // wave (64-lane) reduce
#pragma unroll
        for (int off = 32; off > 0; off >>= 1) {
#pragma unroll
            for (int j = 0; j < COUT / 2; ++j) {
                s[j].x += __shfl_down(s[j].x, off);
                s[j].y += __shfl_down(s[j].y, off);
                q[j].x += __shfl_down(q[j].x, off);
                q[j].y += __shfl_down(q[j].y, off);
            }
        }
        __shared__ float reds[4][2 * COUT];
        const int lane = threadIdx.x & 63, wv = threadIdx.x >> 6;
        if (lane == 0) {
#pragma unroll
            for (int j = 0; j < COUT / 2; ++j) {
                reds[wv][2 * j]            = s[j].x;
                reds[wv][2 * j + 1]        = s[j].y;
                reds[wv][COUT + 2 * j]     = q[j].x;
                reds[wv][COUT + 2 * j + 1] = q[j].y;
            }
        }
        __syncthreads();
        if (threadIdx.x < 2 * COUT) {
            float v = reds[0][threadIdx.x] + reds[1][threadIdx.x] +
                      reds[2][threadIdx.x] + reds[3][threadIdx.x];
            atomicAdd(&stats[threadIdx.x], v);
        }
        if (MODE == 0) {
#pragma unroll
            for (int j = 0; j < COUT / 2; ++j)
#pragma unroll
                for (int hl = 0; hl < 2; ++hl) {
                    const int oc = 2 * j + hl;
#pragma unroll
                    for (int px = 0; px < TPX; ++px) {
                        size_t oidx = (((size_t)(b * COUT + oc)) * HH + (h0 + px)) * WW + w;
                        ws_y[oidx] = __float2bfloat16(hl ? acc[px][j].y : acc[px][j].x);
                    }
                }
        }
    } else { // MODE 2: normalize + relu + write
#pragma unroll
        for (int oc = 0; oc < COUT; ++oc) {
            const float mean = stats[oc] * (1.f / NPC);
            const float var  = stats[COUT + oc] * (1.f / NPC) - mean * mean;
            const float rstd = rsqrtf(var + EPS);
            const float sc = gamma[oc] * rstd;
            const float sh = fmaf(-mean, sc, beta[oc]);
#pragma unroll
            for (int px = 0; px < TPX; ++px) {
                const float av = (oc & 1) ? acc[px][oc / 2].y : acc[px][oc / 2].x;
                size_t oidx = (((size_t)(b * COUT + oc)) * HH + (h0 + px)) * WW + w;
                out[oidx] = fmaxf(fmaf(av, sc, sh), 0.f);
            }
        }
    }
}

// BN+ReLU from bf16 ws, 8 elements/thread
__global__ __launch_bounds__(256)
void bn_kernel(const __hip_bfloat16* __restrict__ ws_y,
               const float* __restrict__ stats,
               const float* __restrict__ gamma,
               const float* __restrict__ beta,
               float* __restrict__ out) {
    const size_t i8 = ((size_t)blockIdx.x * 256 + threadIdx.x) * 8;
    const int oc = (int)((i8 >> 18) & 7);  // HH*WW = 2^18
    const float mean = stats[oc] * (1.f / NPC);
    const float var  = stats[COUT + oc] * (1.f / NPC) - mean * mean;
    const float rstd = rsqrtf(var + EPS);
    const float sc = gamma[oc] * rstd;
    const float sh = fmaf(-mean, sc, beta[oc]);

    const uint4 u = *(const uint4*)((const char*)ws_y + i8 * 2);
    float v[8];
    v[0] = __uint_as_float(u.x << 16);
    v[1] = __uint_as_float(u.x & 0xffff0000u);
    v[2] = __uint_as_float(u.y << 16);
    v[3] = __uint_as_float(u.y & 0xffff0000u);
    v[4] = __uint_as_float(u.z << 16);
    v[5] = __uint_as_float(u.z & 0xffff0000u);
    v[6] = __uint_as_float(u.w << 16);
    v[7] = __uint_as_float(u.w & 0xffff0000u);
    float4 o0, o1;
    o0.x = fmaxf(fmaf(v[0], sc, sh), 0.f);
    o0.y = fmaxf(fmaf(v[1], sc, sh), 0.f);
    o0.z = fmaxf(fmaf(v[2], sc, sh), 0.f);
    o0.w = fmaxf(fmaf(v[3], sc, sh), 0.f);
    o1.x = fmaxf(fmaf(v[4], sc, sh), 0.f);
    o1.y = fmaxf(fmaf(v[5], sc, sh), 0.f);
    o1.z = fmaxf(fmaf(v[6], sc, sh), 0.f);
    o1.w = fmaxf(fmaf(v[7], sc, sh), 0.f);
    *(float4*)(out + i8) = o0;
    *(float4*)(out + i8 + 4) = o1;
}

extern "C" void kernel_launch(void* const* d_in, const int* in_sizes, int n_in,
                              void* d_out, int out_size, void* d_ws, size_t ws_size,
                              hipStream_t stream) {
    const float* x     = (const float*)d_in[0];
    const float* lin_w = (const float*)d_in[1];
    // d_in[2] = lin_b: a per-channel constant shift of conv output, which
    // BatchNorm subtracts back out exactly (mean shifts identically) -> unused.
    const float* gamma = (const float*)d_in[3];
    const float* beta  = (const float*)d_in[4];
    float* out = (float*)d_out;

    float* stats = (float*)d_ws;                                  // 16 floats
    __hip_bfloat16* ws_y = (__hip_bfloat16*)((char*)d_ws + 256);  // conv output, bf16

    const size_t n_elem = (size_t)BATCH * COUT * HH * WW;         // 33,554,432
    const size_t need = 256 + n_elem * 2;

    (void)hipMemsetAsync(d_ws, 0, 256, stream);  // zero stats (ws re-poisoned 0xAA)

    dim3 grid(WW / 256, HH / TPX, BATCH);
    if (ws_size >= need) {
        conv_kernel<0><<<grid, 256, 0, stream>>>(x, lin_w, gamma, beta, ws_y, stats, out);
        bn_kernel<<<(unsigned)(n_elem / (8 * 256)), 256, 0, stream>>>(ws_y, stats, gamma, beta, out);
    } else {
        conv_kernel<1><<<grid, 256, 0, stream>>>(x, lin_w, gamma, beta, ws_y, stats, out);
        conv_kernel<2><<<grid, 256, 0, stream>>>(x, lin_w, gamma, beta, ws_y, stats, out);
    }
}